// Round 1
// baseline (220.980 us; speedup 1.0000x reference)
//
#include <hip/hip_runtime.h>
#include <math.h>

// Problem constants
#define M_ 16
#define N_ 4096
#define D_ 128
#define P_ 8192
#define H_ 32

// Projection tiling
#define NIC 32             // i-chunks over the K(=4096) dim
#define ICH (N_/NIC)       // 128 i per chunk
#define NCB 8              // column blocks of 512 columns

// Attention chunking
#define CHUNK 256
#define NCH (P_/CHUNK)     // 32 cache chunks
#define NCH1 (NCH+1)       // +1 chunk for the 16 appended rows

// Workspace layout (float offsets). proj partials and attn partials overlap
// (sequential lifetimes: k_proj/k_reduce then k_attn/k_comb).
#define QKV_SZ   (3*H_*M_*D_)            // 196608 floats: [mat][h][m][d], mat: 0=qn 1=kn 2=v
#define PART_OFF (QKV_SZ)
#define OPART_OFF (QKV_SZ)
#define OPART_SZ (H_*NCH1*M_*D_)         // 2162688 floats
#define ML_OFF   (OPART_OFF + OPART_SZ)  // 33792 floats (M,L pairs)

// ---------------------------------------------------------------------------
// Kernel 1: partial QKV projection. grid (NCB, NIC, 3), block 256.
// Each thread: 2 output columns x 16 rows, over one 128-long i-chunk.
// ---------------------------------------------------------------------------
__global__ __launch_bounds__(256) void k_proj(const float* __restrict__ X,
                                              const float* __restrict__ Wq,
                                              const float* __restrict__ Wk,
                                              const float* __restrict__ Wv,
                                              float* __restrict__ part) {
  const int mat = blockIdx.z;
  const float* __restrict__ W = (mat == 0) ? Wq : ((mat == 1) ? Wk : Wv);
  const int cb = blockIdx.x, ic = blockIdx.y;
  const int t = threadIdx.x;
  const int j0 = cb * 512 + t * 2;
  const int i0 = ic * ICH;

  __shared__ __align__(16) float XT[ICH][20];  // padded rows (80B, 16B-aligned)

  {
    const int i_l = t & 127, mh = t >> 7;
#pragma unroll
    for (int r = 0; r < 8; ++r)
      XT[i_l][mh * 8 + r] = X[(size_t)(mh * 8 + r) * N_ + i0 + i_l];
  }
  __syncthreads();

  float acc[16][2];
#pragma unroll
  for (int m = 0; m < 16; ++m) { acc[m][0] = 0.f; acc[m][1] = 0.f; }

#pragma unroll 4
  for (int i = 0; i < ICH; ++i) {
    const float2 w = *reinterpret_cast<const float2*>(W + (size_t)(i0 + i) * N_ + j0);
    float xr[16];
    {
      float4 xv;
      xv = *reinterpret_cast<const float4*>(&XT[i][0]);
      xr[0] = xv.x; xr[1] = xv.y; xr[2] = xv.z; xr[3] = xv.w;
      xv = *reinterpret_cast<const float4*>(&XT[i][4]);
      xr[4] = xv.x; xr[5] = xv.y; xr[6] = xv.z; xr[7] = xv.w;
      xv = *reinterpret_cast<const float4*>(&XT[i][8]);
      xr[8] = xv.x; xr[9] = xv.y; xr[10] = xv.z; xr[11] = xv.w;
      xv = *reinterpret_cast<const float4*>(&XT[i][12]);
      xr[12] = xv.x; xr[13] = xv.y; xr[14] = xv.z; xr[15] = xv.w;
    }
#pragma unroll
    for (int m = 0; m < 16; ++m) {
      acc[m][0] = fmaf(xr[m], w.x, acc[m][0]);
      acc[m][1] = fmaf(xr[m], w.y, acc[m][1]);
    }
  }

#pragma unroll
  for (int m = 0; m < 16; ++m) {
    float2 o; o.x = acc[m][0]; o.y = acc[m][1];
    *reinterpret_cast<float2*>(&part[(size_t)((mat * NIC + ic) * M_ + m) * N_ + j0]) = o;
  }
}

// ---------------------------------------------------------------------------
// Kernel 2: reduce i-chunk partials, RMS-norm q/k, relayout to [mat][h][m][d].
// grid (16 n-chunks, 16 m, 3 mat), block 256 (covers 2 heads).
// ---------------------------------------------------------------------------
__global__ __launch_bounds__(256) void k_reduce(const float* __restrict__ part,
                                                float* __restrict__ qkv) {
  const int mat = blockIdx.z, m = blockIdx.y, nc = blockIdx.x;
  const int t = threadIdx.x;
  const int n = nc * 256 + t;

  float s = 0.f;
#pragma unroll
  for (int ic = 0; ic < NIC; ++ic)
    s += part[(size_t)((mat * NIC + ic) * M_ + m) * N_ + n];

  // sum of squares over each head (128 consecutive n = 2 waves)
  float ss = s * s;
#pragma unroll
  for (int off = 1; off < 64; off <<= 1) ss += __shfl_xor(ss, off);
  __shared__ float wsum[4];
  const int wave = t >> 6, lane = t & 63;
  if (lane == 0) wsum[wave] = ss;
  __syncthreads();
  const int half = t >> 7;
  const float tot = wsum[half * 2] + wsum[half * 2 + 1];
  const float scale = (mat < 2) ? rsqrtf(tot * (1.0f / 128.0f)) : 1.0f;

  const int h = n >> 7, d = n & 127;
  qkv[(size_t)((mat * H_ + h) * M_ + m) * D_ + d] = s * scale;
}

// ---------------------------------------------------------------------------
// Kernel 3: split-P attention partials. grid (NCH1, H_), block 256.
// Chunk c<32: 256 cache rows. Chunk 32: the 16 appended (k_norm, v) rows.
// K/V tiles staged in LDS with a 16B-block rotation swizzle:
//   slot16B = (blk + (row/4)) & 31   -> ds_read_b128 at the 8-cyc floor.
// ---------------------------------------------------------------------------
__global__ __launch_bounds__(256) void k_attn(const float* __restrict__ cacheK,
                                              const float* __restrict__ cacheV,
                                              const float* __restrict__ qkv,
                                              float* __restrict__ opart,
                                              float* __restrict__ ml) {
  const int c = blockIdx.x;   // 0..32
  const int h = blockIdx.y;
  const int t = threadIdx.x;
  const int valid = (c < NCH) ? CHUNK : M_;
  const float* __restrict__ Ksrc = (c < NCH)
      ? (cacheK + ((size_t)h * P_ + (size_t)c * CHUNK) * D_)
      : (qkv + (size_t)((1 * H_ + h) * M_) * D_);
  const float* __restrict__ Vsrc = (c < NCH)
      ? (cacheV + ((size_t)h * P_ + (size_t)c * CHUNK) * D_)
      : (qkv + (size_t)((2 * H_ + h) * M_) * D_);

  __shared__ __align__(16) float qs[M_ * D_];     // 8 KB
  __shared__ __align__(16) float kvt[32 * D_];    // 16 KB K/V subtile (swizzled)
  __shared__ __align__(16) float sc[M_ * 264];    // 16.9 KB scores/weights (pad 264)
  __shared__ float red[M_ * 16];
  __shared__ float Mrow[M_], Lrow[M_];

  // stage q (16x128)
  {
    const float4* src = reinterpret_cast<const float4*>(qkv + (size_t)((0 * H_ + h) * M_) * D_);
    float4* dst = reinterpret_cast<float4*>(qs);
    dst[t] = src[t];
    dst[t + 256] = src[t + 256];
  }

  const int mg = t >> 6, pg = (t >> 3) & 7, dq = t & 7;
  const int m0 = mg * 4;

  // ---- Phase A: scores -----------------------------------------------------
  for (int st = 0; st < 8; ++st) {
    __syncthreads();  // kvt free (and qs staged on first iter)
    // stage K subtile rows [st*32, st*32+32)
#pragma unroll
    for (int k = 0; k < 4; ++k) {
      const int id = t + k * 256;
      const int row = id >> 5, blk = id & 31;
      const int gp = st * 32 + row;
      float4 v;
      if (gp < valid) v = reinterpret_cast<const float4*>(Ksrc)[(size_t)gp * 32 + blk];
      else { v.x = 0.f; v.y = 0.f; v.z = 0.f; v.w = 0.f; }
      const int slot = (blk + (row >> 2)) & 31;
      *reinterpret_cast<float4*>(&kvt[row * D_ + slot * 4]) = v;
    }
    __syncthreads();

    float a[4][4];
#pragma unroll
    for (int mi = 0; mi < 4; ++mi)
#pragma unroll
      for (int pi = 0; pi < 4; ++pi) a[mi][pi] = 0.f;

#pragma unroll
    for (int dd = 0; dd < 4; ++dd) {
      const int d = dq * 16 + dd * 4;
      float4 qv[4], kv4[4];
#pragma unroll
      for (int mi = 0; mi < 4; ++mi)
        qv[mi] = *reinterpret_cast<const float4*>(&qs[(m0 + mi) * D_ + d]);
#pragma unroll
      for (int pi = 0; pi < 4; ++pi) {
        const int pr = pg * 4 + pi;
        const int slot = ((d >> 2) + (pr >> 2)) & 31;
        kv4[pi] = *reinterpret_cast<const float4*>(&kvt[pr * D_ + slot * 4]);
      }
#pragma unroll
      for (int mi = 0; mi < 4; ++mi)
#pragma unroll
        for (int pi = 0; pi < 4; ++pi)
          a[mi][pi] += qv[mi].x * kv4[pi].x + qv[mi].y * kv4[pi].y +
                       qv[mi].z * kv4[pi].z + qv[mi].w * kv4[pi].w;
    }
    // reduce d-partials across the 8 dq lanes (within-wave)
#pragma unroll
    for (int off = 1; off < 8; off <<= 1)
#pragma unroll
      for (int mi = 0; mi < 4; ++mi)
#pragma unroll
        for (int pi = 0; pi < 4; ++pi)
          a[mi][pi] += __shfl_xor(a[mi][pi], off);
    // lanes dq==r write row m0+r (compile-time indices; conflict-free groups)
#pragma unroll
    for (int r = 0; r < 4; ++r) {
      if (dq == r) {
        float4 o; o.x = a[r][0]; o.y = a[r][1]; o.z = a[r][2]; o.w = a[r][3];
        *reinterpret_cast<float4*>(&sc[(m0 + r) * 264 + st * 32 + pg * 4]) = o;
      }
    }
  }
  __syncthreads();

  // ---- Phase B: chunk softmax ---------------------------------------------
  {
    const int m = t >> 4, seg = t & 15;
    float mx = -3.0e38f;
#pragma unroll
    for (int j = 0; j < 16; ++j) {
      const int p = seg * 16 + j;
      if (p < valid) mx = fmaxf(mx, sc[m * 264 + p]);
    }
    red[m * 16 + seg] = mx;
    __syncthreads();
    if (t < 16) {
      float v = red[t * 16];
      for (int k2 = 1; k2 < 16; ++k2) v = fmaxf(v, red[t * 16 + k2]);
      Mrow[t] = v;
    }
    __syncthreads();
    const float Mm = Mrow[m];
    float ls = 0.f;
#pragma unroll
    for (int j = 0; j < 16; ++j) {
      const int p = seg * 16 + j;
      float w2 = 0.f;
      if (p < valid) w2 = __expf(sc[m * 264 + p] - Mm);
      sc[m * 264 + p] = w2;
      ls += w2;
    }
    red[m * 16 + seg] = ls;
    __syncthreads();
    if (t < 16) {
      float v = 0.f;
      for (int k2 = 0; k2 < 16; ++k2) v += red[t * 16 + k2];
      Lrow[t] = v;
    }
  }
  __syncthreads();

  // ---- Phase C: PV ---------------------------------------------------------
  const int dg = (t >> 2) & 15, ps = t & 3;  // mg reused; p = ps + 4*pi
  float acc[4][8];
#pragma unroll
  for (int mi = 0; mi < 4; ++mi)
#pragma unroll
    for (int j = 0; j < 8; ++j) acc[mi][j] = 0.f;

  for (int st = 0; st < 8; ++st) {
    // stage V subtile (kvt protected by trailing sync of previous iteration)
#pragma unroll
    for (int k = 0; k < 4; ++k) {
      const int id = t + k * 256;
      const int row = id >> 5, blk = id & 31;
      const int gp = st * 32 + row;
      float4 v;
      if (gp < valid) v = reinterpret_cast<const float4*>(Vsrc)[(size_t)gp * 32 + blk];
      else { v.x = 0.f; v.y = 0.f; v.z = 0.f; v.w = 0.f; }
      const int slot = (blk + (row >> 2)) & 31;
      *reinterpret_cast<float4*>(&kvt[row * D_ + slot * 4]) = v;
    }
    __syncthreads();
#pragma unroll
    for (int pi = 0; pi < 8; ++pi) {
      const int pl = ps + pi * 4;
      const int slot0 = (dg + pi) & 31;         // d-block dg, rotation = pl>>2 = pi
      const int slot1 = (dg + 16 + pi) & 31;    // d-block 16+dg
      const float4 v0 = *reinterpret_cast<const float4*>(&kvt[pl * D_ + slot0 * 4]);
      const float4 v1 = *reinterpret_cast<const float4*>(&kvt[pl * D_ + slot1 * 4]);
#pragma unroll
      for (int mi = 0; mi < 4; ++mi) {
        const float w2 = sc[(m0 + mi) * 264 + st * 32 + pl];
        acc[mi][0] = fmaf(w2, v0.x, acc[mi][0]);
        acc[mi][1] = fmaf(w2, v0.y, acc[mi][1]);
        acc[mi][2] = fmaf(w2, v0.z, acc[mi][2]);
        acc[mi][3] = fmaf(w2, v0.w, acc[mi][3]);
        acc[mi][4] = fmaf(w2, v1.x, acc[mi][4]);
        acc[mi][5] = fmaf(w2, v1.y, acc[mi][5]);
        acc[mi][6] = fmaf(w2, v1.z, acc[mi][6]);
        acc[mi][7] = fmaf(w2, v1.w, acc[mi][7]);
      }
    }
    __syncthreads();
  }

  // combine the 4 ps-partials into ob (aliases sc; weights no longer needed)
  float* ob = sc;  // 16 x 128, stride 128
#pragma unroll
  for (int r = 0; r < 4; ++r) {
    if (ps == r) {
#pragma unroll
      for (int mi = 0; mi < 4; ++mi) {
        float4* d0 = reinterpret_cast<float4*>(&ob[(m0 + mi) * D_ + dg * 4]);
        float4* d1 = reinterpret_cast<float4*>(&ob[(m0 + mi) * D_ + 64 + dg * 4]);
        if (r == 0) {
          float4 o0; o0.x = acc[mi][0]; o0.y = acc[mi][1]; o0.z = acc[mi][2]; o0.w = acc[mi][3];
          float4 o1; o1.x = acc[mi][4]; o1.y = acc[mi][5]; o1.z = acc[mi][6]; o1.w = acc[mi][7];
          *d0 = o0; *d1 = o1;
        } else {
          float4 o0 = *d0, o1 = *d1;
          o0.x += acc[mi][0]; o0.y += acc[mi][1]; o0.z += acc[mi][2]; o0.w += acc[mi][3];
          o1.x += acc[mi][4]; o1.y += acc[mi][5]; o1.z += acc[mi][6]; o1.w += acc[mi][7];
          *d0 = o0; *d1 = o1;
        }
      }
    }
    __syncthreads();
  }

  // write partial O + (M, L)
  {
    const size_t base = (size_t)((h * NCH1 + c) * M_) * D_;
    float4* op4 = reinterpret_cast<float4*>(opart + base);
    const float4* ob4 = reinterpret_cast<const float4*>(ob);
    op4[t] = ob4[t];
    op4[t + 256] = ob4[t + 256];
    if (t < 16) {
      ml[((size_t)(h * NCH1 + c) * M_ + t) * 2 + 0] = Mrow[t];
      ml[((size_t)(h * NCH1 + c) * M_ + t) * 2 + 1] = Lrow[t];
    }
  }
}

// ---------------------------------------------------------------------------
// Kernel 4: combine 33 chunk partials per (h, m). grid (M_, H_), block 128.
// ---------------------------------------------------------------------------
__global__ __launch_bounds__(128) void k_comb(const float* __restrict__ opart,
                                              const float* __restrict__ ml,
                                              float* __restrict__ out) {
  const int m = blockIdx.x, h = blockIdx.y, t = threadIdx.x;
  __shared__ float Ms[NCH1], Ls[NCH1];
  if (t < NCH1) {
    Ms[t] = ml[((size_t)(h * NCH1 + t) * M_ + m) * 2 + 0];
    Ls[t] = ml[((size_t)(h * NCH1 + t) * M_ + m) * 2 + 1];
  }
  __syncthreads();
  float gM = -3.0e38f;
#pragma unroll
  for (int c2 = 0; c2 < NCH1; ++c2) gM = fmaxf(gM, Ms[c2]);
  float T = 0.f, o = 0.f;
  for (int c2 = 0; c2 < NCH1; ++c2) {
    const float f = __expf(Ms[c2] - gM);
    T = fmaf(Ls[c2], f, T);
    o = fmaf(opart[((size_t)(h * NCH1 + c2) * M_ + m) * D_ + t], f, o);
  }
  out[(size_t)m * N_ + h * D_ + t] = o / T;
}

// ---------------------------------------------------------------------------
extern "C" void kernel_launch(void* const* d_in, const int* in_sizes, int n_in,
                              void* d_out, int out_size, void* d_ws, size_t ws_size,
                              hipStream_t stream) {
  const float* X  = (const float*)d_in[0];
  const float* Wq = (const float*)d_in[1];
  const float* Wk = (const float*)d_in[2];
  const float* Wv = (const float*)d_in[3];
  const float* cK = (const float*)d_in[4];
  const float* cV = (const float*)d_in[5];
  float* ws    = (float*)d_ws;
  float* qkv   = ws;              // [3][H][M][D]
  float* part  = ws + PART_OFF;   // proj partials (dead after k_reduce)
  float* opart = ws + OPART_OFF;  // attn partials (overlaps part)
  float* mlbuf = ws + ML_OFF;
  float* out   = (float*)d_out;

  hipLaunchKernelGGL(k_proj,   dim3(NCB, NIC, 3), dim3(256), 0, stream, X, Wq, Wk, Wv, part);
  hipLaunchKernelGGL(k_reduce, dim3(16, M_, 3),   dim3(256), 0, stream, part, qkv);
  hipLaunchKernelGGL(k_attn,   dim3(NCH1, H_),    dim3(256), 0, stream, cK, cV, qkv, opart, mlbuf);
  hipLaunchKernelGGL(k_comb,   dim3(M_, H_),      dim3(128), 0, stream, opart, mlbuf, out);
}

// Round 2
// 159.809 us; speedup vs baseline: 1.3828x; 1.3828x over previous
//
#include <hip/hip_runtime.h>
#include <math.h>

// Problem constants
#define M_ 16
#define N_ 4096
#define D_ 128
#define P_ 8192
#define H_ 32

// Projection tiling
#define NIC 32
#define ICH (N_/NIC)
#define NCB 8

// Attention chunking
#define CHUNK 256
#define NCH (P_/CHUNK)
#define NCH1 (NCH+1)

// Workspace layout (float offsets)
#define QKV_SZ    (3*H_*M_*D_)
#define PART_OFF  (QKV_SZ)
#define OPART_OFF (QKV_SZ)
#define OPART_SZ  (H_*NCH1*M_*D_)
#define ML_OFF    (OPART_OFF + OPART_SZ)

// raw sync helpers (counted vmcnt pipeline — do NOT use __syncthreads in k_attn)
#define BAR()       asm volatile("s_barrier" ::: "memory")
#define WAIT_VM4()  asm volatile("s_waitcnt vmcnt(4)" ::: "memory")
#define WAIT_VM0()  asm volatile("s_waitcnt vmcnt(0)" ::: "memory")
#define WAIT_LGKM() asm volatile("s_waitcnt lgkmcnt(0)" ::: "memory")

__device__ __forceinline__ void gl_lds16(const float* src, float* dst) {
  __builtin_amdgcn_global_load_lds(
      (const __attribute__((address_space(1))) void*)src,
      (__attribute__((address_space(3))) void*)dst, 16, 0, 0);
}

// ---------------------------------------------------------------------------
// Kernel 1: partial QKV projection. grid (NCB, NIC, 3), block 256. (unchanged)
// ---------------------------------------------------------------------------
__global__ __launch_bounds__(256) void k_proj(const float* __restrict__ X,
                                              const float* __restrict__ Wq,
                                              const float* __restrict__ Wk,
                                              const float* __restrict__ Wv,
                                              float* __restrict__ part) {
  const int mat = blockIdx.z;
  const float* __restrict__ W = (mat == 0) ? Wq : ((mat == 1) ? Wk : Wv);
  const int cb = blockIdx.x, ic = blockIdx.y;
  const int t = threadIdx.x;
  const int j0 = cb * 512 + t * 2;
  const int i0 = ic * ICH;

  __shared__ __align__(16) float XT[ICH][20];

  {
    const int i_l = t & 127, mh = t >> 7;
#pragma unroll
    for (int r = 0; r < 8; ++r)
      XT[i_l][mh * 8 + r] = X[(size_t)(mh * 8 + r) * N_ + i0 + i_l];
  }
  __syncthreads();

  float acc[16][2];
#pragma unroll
  for (int m = 0; m < 16; ++m) { acc[m][0] = 0.f; acc[m][1] = 0.f; }

#pragma unroll 4
  for (int i = 0; i < ICH; ++i) {
    const float2 w = *reinterpret_cast<const float2*>(W + (size_t)(i0 + i) * N_ + j0);
    float xr[16];
    {
      float4 xv;
      xv = *reinterpret_cast<const float4*>(&XT[i][0]);
      xr[0] = xv.x; xr[1] = xv.y; xr[2] = xv.z; xr[3] = xv.w;
      xv = *reinterpret_cast<const float4*>(&XT[i][4]);
      xr[4] = xv.x; xr[5] = xv.y; xr[6] = xv.z; xr[7] = xv.w;
      xv = *reinterpret_cast<const float4*>(&XT[i][8]);
      xr[8] = xv.x; xr[9] = xv.y; xr[10] = xv.z; xr[11] = xv.w;
      xv = *reinterpret_cast<const float4*>(&XT[i][12]);
      xr[12] = xv.x; xr[13] = xv.y; xr[14] = xv.z; xr[15] = xv.w;
    }
#pragma unroll
    for (int m = 0; m < 16; ++m) {
      acc[m][0] = fmaf(xr[m], w.x, acc[m][0]);
      acc[m][1] = fmaf(xr[m], w.y, acc[m][1]);
    }
  }

#pragma unroll
  for (int m = 0; m < 16; ++m) {
    float2 o; o.x = acc[m][0]; o.y = acc[m][1];
    *reinterpret_cast<float2*>(&part[(size_t)((mat * NIC + ic) * M_ + m) * N_ + j0]) = o;
  }
}

// ---------------------------------------------------------------------------
// Kernel 2: reduce partials, RMS-norm q/k, relayout. (unchanged)
// ---------------------------------------------------------------------------
__global__ __launch_bounds__(256) void k_reduce(const float* __restrict__ part,
                                                float* __restrict__ qkv) {
  const int mat = blockIdx.z, m = blockIdx.y, nc = blockIdx.x;
  const int t = threadIdx.x;
  const int n = nc * 256 + t;

  float s = 0.f;
#pragma unroll
  for (int ic = 0; ic < NIC; ++ic)
    s += part[(size_t)((mat * NIC + ic) * M_ + m) * N_ + n];

  float ss = s * s;
#pragma unroll
  for (int off = 1; off < 64; off <<= 1) ss += __shfl_xor(ss, off);
  __shared__ float wsum[4];
  const int wave = t >> 6, lane = t & 63;
  if (lane == 0) wsum[wave] = ss;
  __syncthreads();
  const int half = t >> 7;
  const float tot = wsum[half * 2] + wsum[half * 2 + 1];
  const float scale = (mat < 2) ? rsqrtf(tot * (1.0f / 128.0f)) : 1.0f;

  const int h = n >> 7, d = n & 127;
  qkv[(size_t)((mat * H_ + h) * M_ + m) * D_ + d] = s * scale;
}

// ---------------------------------------------------------------------------
// Kernel 3: split-P attention. grid (NCH1, H_), block 256 (4 waves).
// Counted-vmcnt double-buffered pipeline:
//   prologue: q->regs (16 loads), STAGE(K0), STAGE(K1)
//   A st=0..7: vmcnt(4); bar; QK^T(buf); lgkm0; bar; STAGE(u=st+2)  [u>=8 -> V]
//   B: chunk softmax into transposed sct[256][20]
//   C st=0..7: vmcnt(4|0); bar; PV(buf); lgkm0; bar; if st<=5 STAGE(V st+2)
// LDS rotation swizzle slot=(b+row)&31, staged via pre-swizzled GLOBAL source
// (global_load_lds dest must stay linear). Each wave stages its own 8 rows and
// waits only its own vmcnt; the barrier makes completion collective.
// ---------------------------------------------------------------------------
__global__ __launch_bounds__(256) void k_attn(const float* __restrict__ cacheK,
                                              const float* __restrict__ cacheV,
                                              const float* __restrict__ qkv,
                                              float* __restrict__ opart,
                                              float* __restrict__ ml) {
  const int c = blockIdx.x, h = blockIdx.y;
  const int t = threadIdx.x;
  const int wave = t >> 6, lane = t & 63;
  const int valid = (c < NCH) ? CHUNK : M_;
  const float* __restrict__ Ksrc = (c < NCH)
      ? (cacheK + ((size_t)h * P_ + (size_t)c * CHUNK) * D_)
      : (qkv + (size_t)((1 * H_ + h) * M_) * D_);
  const float* __restrict__ Vsrc = (c < NCH)
      ? (cacheV + ((size_t)h * P_ + (size_t)c * CHUNK) * D_)
      : (qkv + (size_t)((2 * H_ + h) * M_) * D_);

  __shared__ __align__(16) float kvf[2 * 32 * 128];   // 32 KB, 2 staging buffers
  __shared__ __align__(16) float sct[256 * 20];       // 20 KB scores^T [p][m], pad 20
  __shared__ float red[256];
  __shared__ float Mrow[M_], Lrow[M_];

  // ---- q into registers. lane = (pg, dq); wave owns m0..m0+3.
  const int pg = lane >> 3, dq = lane & 7;
  const int m0 = wave * 4;
  float4 qr[4][4];  // [mi][dd] = q[m0+mi][dq*4 + dd*32 .. +4)
  {
    const float* qb = qkv + (size_t)((0 * H_ + h) * M_) * D_;
#pragma unroll
    for (int mi = 0; mi < 4; ++mi)
#pragma unroll
      for (int dd = 0; dd < 4; ++dd)
        qr[mi][dd] = *reinterpret_cast<const float4*>(qb + (m0 + mi) * D_ + dq * 4 + dd * 32);
  }

  // STAGE(u): u<8 -> K subtile u; u>=8 -> V subtile u-8. Buffer = u&1.
  // Wave stages rows [wave*8, wave*8+8) = 4 insts x (2 rows x 1KB).
  // LDS linear; source block pre-rotated: content[row][(b+row)&31] = src[row][b].
  auto STAGE = [&](int u) {
    const float* sb = (u < 8) ? Ksrc : Vsrc;
    const int sst = (u < 8) ? u : u - 8;
    float* tb = &kvf[(u & 1) * 4096];
    const int s = lane & 31, rh5 = lane >> 5;
#pragma unroll
    for (int k = 0; k < 4; ++k) {
      const int row = wave * 8 + k * 2 + rh5;
      int gp = sst * 32 + row; gp = (gp < valid) ? gp : (valid - 1);
      const int b = (s - row) & 31;
      gl_lds16(sb + (size_t)gp * D_ + b * 4, tb + (wave * 8 + k * 2) * D_);
    }
  };

  STAGE(0);
  STAGE(1);

  // ---- Phase A: scores^T -> sct ------------------------------------------
#pragma unroll 1
  for (int st = 0; st < 8; ++st) {
    WAIT_VM4();   // my 4 loads for this buffer done (all but newest 4)
    BAR();
    const float* tile = &kvf[(st & 1) * 4096];
    float a[4][4];
#pragma unroll
    for (int mi = 0; mi < 4; ++mi)
#pragma unroll
      for (int pi = 0; pi < 4; ++pi) a[mi][pi] = 0.f;

#pragma unroll
    for (int pi = 0; pi < 4; ++pi) {
      const int row = pg + 8 * pi;
#pragma unroll
      for (int dd = 0; dd < 4; ++dd) {
        const int slot = ((dq + 8 * dd) + row) & 31;
        const float4 kk = *reinterpret_cast<const float4*>(tile + row * D_ + slot * 4);
#pragma unroll
        for (int mi = 0; mi < 4; ++mi) {
          a[mi][pi] = fmaf(qr[mi][dd].x, kk.x, a[mi][pi]);
          a[mi][pi] = fmaf(qr[mi][dd].y, kk.y, a[mi][pi]);
          a[mi][pi] = fmaf(qr[mi][dd].z, kk.z, a[mi][pi]);
          a[mi][pi] = fmaf(qr[mi][dd].w, kk.w, a[mi][pi]);
        }
      }
    }
    // reduce the d-split over the 8 dq lanes
#pragma unroll
    for (int off = 1; off < 8; off <<= 1)
#pragma unroll
      for (int mi = 0; mi < 4; ++mi)
#pragma unroll
        for (int pi = 0; pi < 4; ++pi)
          a[mi][pi] += __shfl_xor(a[mi][pi], off);
    // transposed score write: lane dq==mi writes its 4 rows
#pragma unroll
    for (int mi = 0; mi < 4; ++mi) {
      if (dq == mi) {
#pragma unroll
        for (int pi = 0; pi < 4; ++pi)
          sct[(st * 32 + pg + 8 * pi) * 20 + m0 + mi] = a[mi][pi];
      }
    }
    WAIT_LGKM();  // my ds reads/writes done -> buffer reusable, sct visible
    BAR();
    STAGE(st + 2);  // u = 2..9 : K2..K7, V0, V1
  }

  // ---- Phase B: chunk softmax (sct[p][m] -> weights) -----------------------
  {
    const int bm = t & 15, seg = t >> 4;
    float mx = -3.0e38f;
#pragma unroll
    for (int j = 0; j < 16; ++j) {
      const int p = seg * 16 + j;
      if (p < valid) mx = fmaxf(mx, sct[p * 20 + bm]);
    }
    red[bm * 16 + seg] = mx;
    WAIT_LGKM(); BAR();
    if (t < 16) {
      float v = red[t * 16];
#pragma unroll
      for (int k2 = 1; k2 < 16; ++k2) v = fmaxf(v, red[t * 16 + k2]);
      Mrow[t] = v;
    }
    WAIT_LGKM(); BAR();
    const float Mm = Mrow[bm];
    float ls = 0.f;
#pragma unroll
    for (int j = 0; j < 16; ++j) {
      const int p = seg * 16 + j;
      float w2 = 0.f;
      if (p < valid) w2 = __expf(sct[p * 20 + bm] - Mm);
      sct[p * 20 + bm] = w2;   // unconditional: zeros the invalid tail rows
      ls += w2;
    }
    red[bm * 16 + seg] = ls;
    WAIT_LGKM(); BAR();
    if (t < 16) {
      float v = 0.f;
#pragma unroll
      for (int k2 = 0; k2 < 16; ++k2) v += red[t * 16 + k2];
      Lrow[t] = v;
    }
    WAIT_LGKM(); BAR();
  }

  // ---- Phase C: PV. Wave owns 8 rows/subtile; lane = (b31, rh) owns
  // m-range rh*8..rh*8+7 x d-block b31. acc = 8 float4 (32 VGPR).
  const int b31 = lane & 31, rh = lane >> 5;
  float4 macc[8];
#pragma unroll
  for (int i = 0; i < 8; ++i) macc[i] = make_float4(0.f, 0.f, 0.f, 0.f);

#pragma unroll 1
  for (int st = 0; st < 8; ++st) {
    if (st == 7) { WAIT_VM0(); } else { WAIT_VM4(); }
    BAR();
    const float* tile = &kvf[(st & 1) * 4096];
#pragma unroll
    for (int j = 0; j < 8; ++j) {
      const int row = wave * 8 + j;
      const int slot = (b31 + row) & 31;
      const float4 v4 = *reinterpret_cast<const float4*>(tile + row * D_ + slot * 4);
      const int p = st * 32 + row;
      const float4 w0 = *reinterpret_cast<const float4*>(&sct[p * 20 + rh * 8]);
      const float4 w1 = *reinterpret_cast<const float4*>(&sct[p * 20 + rh * 8 + 4]);
#define PVROW(i, wc) \
      macc[i].x = fmaf(wc, v4.x, macc[i].x); \
      macc[i].y = fmaf(wc, v4.y, macc[i].y); \
      macc[i].z = fmaf(wc, v4.z, macc[i].z); \
      macc[i].w = fmaf(wc, v4.w, macc[i].w);
      PVROW(0, w0.x) PVROW(1, w0.y) PVROW(2, w0.z) PVROW(3, w0.w)
      PVROW(4, w1.x) PVROW(5, w1.y) PVROW(6, w1.z) PVROW(7, w1.w)
#undef PVROW
    }
    WAIT_LGKM();
    BAR();
    if (st <= 5) STAGE(st + 10);  // V2..V7
  }

  // ---- Epilogue: cross-wave reduce through dead staging buffers ------------
  float* ep = kvf;  // [4 waves][16 m][128 d] = 32 KB
#pragma unroll
  for (int i = 0; i < 8; ++i)
    *reinterpret_cast<float4*>(ep + wave * 2048 + (rh * 8 + i) * D_ + b31 * 4) = macc[i];
  WAIT_LGKM(); BAR();
  {
    const size_t base = (size_t)((h * NCH1 + c) * M_) * D_;
    float4* op4 = reinterpret_cast<float4*>(opart + base);
    const float4* e4 = reinterpret_cast<const float4*>(ep);
#pragma unroll
    for (int r = 0; r < 2; ++r) {
      const int i4 = t + r * 256;
      const float4 s0 = e4[i4], s1 = e4[i4 + 512], s2 = e4[i4 + 1024], s3 = e4[i4 + 1536];
      float4 o;
      o.x = s0.x + s1.x + s2.x + s3.x;
      o.y = s0.y + s1.y + s2.y + s3.y;
      o.z = s0.z + s1.z + s2.z + s3.z;
      o.w = s0.w + s1.w + s2.w + s3.w;
      op4[i4] = o;
    }
    if (t < 16) {
      ml[((size_t)(h * NCH1 + c) * M_ + t) * 2 + 0] = Mrow[t];
      ml[((size_t)(h * NCH1 + c) * M_ + t) * 2 + 1] = Lrow[t];
    }
  }
}

// ---------------------------------------------------------------------------
// Kernel 4: combine 33 chunk partials per (h, m). (unchanged)
// ---------------------------------------------------------------------------
__global__ __launch_bounds__(128) void k_comb(const float* __restrict__ opart,
                                              const float* __restrict__ ml,
                                              float* __restrict__ out) {
  const int m = blockIdx.x, h = blockIdx.y, t = threadIdx.x;
  __shared__ float Ms[NCH1], Ls[NCH1];
  if (t < NCH1) {
    Ms[t] = ml[((size_t)(h * NCH1 + t) * M_ + m) * 2 + 0];
    Ls[t] = ml[((size_t)(h * NCH1 + t) * M_ + m) * 2 + 1];
  }
  __syncthreads();
  float gM = -3.0e38f;
#pragma unroll
  for (int c2 = 0; c2 < NCH1; ++c2) gM = fmaxf(gM, Ms[c2]);
  float T = 0.f, o = 0.f;
  for (int c2 = 0; c2 < NCH1; ++c2) {
    const float f = __expf(Ms[c2] - gM);
    T = fmaf(Ls[c2], f, T);
    o = fmaf(opart[((size_t)(h * NCH1 + c2) * M_ + m) * D_ + t], f, o);
  }
  out[(size_t)m * N_ + h * D_ + t] = o / T;
}

// ---------------------------------------------------------------------------
extern "C" void kernel_launch(void* const* d_in, const int* in_sizes, int n_in,
                              void* d_out, int out_size, void* d_ws, size_t ws_size,
                              hipStream_t stream) {
  const float* X  = (const float*)d_in[0];
  const float* Wq = (const float*)d_in[1];
  const float* Wk = (const float*)d_in[2];
  const float* Wv = (const float*)d_in[3];
  const float* cK = (const float*)d_in[4];
  const float* cV = (const float*)d_in[5];
  float* ws    = (float*)d_ws;
  float* qkv   = ws;
  float* part  = ws + PART_OFF;
  float* opart = ws + OPART_OFF;
  float* mlbuf = ws + ML_OFF;
  float* out   = (float*)d_out;

  hipLaunchKernelGGL(k_proj,   dim3(NCB, NIC, 3), dim3(256), 0, stream, X, Wq, Wk, Wv, part);
  hipLaunchKernelGGL(k_reduce, dim3(16, M_, 3),   dim3(256), 0, stream, part, qkv);
  hipLaunchKernelGGL(k_attn,   dim3(NCH1, H_),    dim3(256), 0, stream, cK, cV, qkv, opart, mlbuf);
  hipLaunchKernelGGL(k_comb,   dim3(M_, H_),      dim3(128), 0, stream, opart, mlbuf, out);
}